// Round 23
// baseline (30.329 us; speedup 1.0000x reference)
//
#include <hip/hip_runtime.h>
#include <math.h>

// VolumeSDFRenderer — 32 lanes/ray, 2 rays/wave, streaming-tuned.
// Absorb-critical XLA base-16 cascade bit-ORDER-exact (R17-R22, absmax
// pinned at bf16 comparator floor 0.0039): in-lane 4-add folds + 3-step
// segmented ripple -> chunk sums (lane q=31 stops at x126 -> L);
// P7 = seq scan of S0..S6; y = fl(fl(L+x127)+P7); t = y-x127. PINs forbid
// fma contraction / (C+x)-x folding / exp-arg distribution.
//
// R22 -> R23 (R22 showed compute cuts no longer move wall time; effective
// read throughput 5.35 TB/s ~= 85% of the 6.3 TB/s D2D ceiling -> memory-
// streaming bound, latency/occupancy tuning only):
//  * __launch_bounds__(256, 8): lift occupancy cap (VGPR 20 permits).
//  * zb gather (16B-stride scalar load) -> __shfl_down(zv.x,1): the value
//    already sits in the next lane's register; q==31 junk masked by the
//    1e10 ternary. Saves 1 VMEM instr + L1 traffic per lane.
//  * all global loads hoisted to kernel top: 6 VMEM ops in flight before
//    any dependent VALU.

#define N_PTS 128
#define PIN(v) asm volatile("" : "+v"(v))

__global__ __launch_bounds__(256, 8) void vr23_stream(
    const float* __restrict__ distance,
    const float* __restrict__ color,
    const float* __restrict__ depth,
    float* __restrict__ out,
    int n_rays)
{
    const int lane = threadIdx.x & 63;
    const int wv   = threadIdx.x >> 6;
    const int h    = lane >> 5;               // half: ray select
    const int q    = lane & 31;               // lane within ray
    const int ray  = blockIdx.x * 8 + wv * 2 + h;
    if (ray >= n_rays) return;

    // ---- ALL loads issued up front (coalesced float4) ----
    float4 dv = ((const float4*)(distance + (size_t)ray * N_PTS))[q];
    float4 zv = ((const float4*)(depth    + (size_t)ray * N_PTS))[q];
    const float4* c4 = (const float4*)(color + (size_t)ray * 384 + q * 12);
    float4 ca = c4[0];   // p0.r p0.g p0.b p1.r
    float4 cb = c4[1];   // p1.g p1.b p2.r p2.g
    float4 cd = c4[2];   // p2.b p3.r p3.g p3.b

    // depth[4q+4] from the next lane's register (q==31 masked below)
    float zb = __shfl_down(zv.x, 1);

    // ---- density (np op order; rcp keeps /inf -> +0) ----
    float e0 = __expf(-150.0f * dv.x), o0 = 1.0f + e0;
    float den0 = (150.0f * e0) * __builtin_amdgcn_rcpf(o0 * o0);
    float e1 = __expf(-150.0f * dv.y), o1 = 1.0f + e1;
    float den1 = (150.0f * e1) * __builtin_amdgcn_rcpf(o1 * o1);
    float e2 = __expf(-150.0f * dv.z), o2 = 1.0f + e2;
    float den2 = (150.0f * e2) * __builtin_amdgcn_rcpf(o2 * o2);
    float e3 = __expf(-150.0f * dv.w), o3 = 1.0f + e3;
    float den3 = (150.0f * e3) * __builtin_amdgcn_rcpf(o3 * o3);

    float d0 = zv.y - zv.x;
    float d1 = zv.z - zv.y;
    float d2 = zv.w - zv.z;
    float d3 = (q == 31) ? 1e10f : (zb - zv.w);

    float x0 = d0 * den0; PIN(x0);
    float x1 = d1 * den1; PIN(x1);
    float x2 = d2 * den2; PIN(x2);
    float x3 = d3 * den3; PIN(x3);            // q==31: x127 (huge)

    // ---- chunk sums: in-lane seq fold + 3-step segmented ripple ----
    float P;
    {
        float f = x0;
        f = f + x1; PIN(f);
        f = f + x2; PIN(f);
        float g2 = f + x3; PIN(g2);
        P = ((q & 3) == 0) ? g2 : 0.0f;
    }
    #pragma unroll
    for (int j = 1; j < 4; ++j) {
        float v = __shfl_up(P, 1);
        if ((q & 3) == j) {
            float f = v + x0; PIN(f);
            f = f + x1; PIN(f);
            f = f + x2; PIN(f);
            if (q == 31) {
                P = f;                        // L = seq(x112..x126)
            } else {
                f = f + x3; PIN(f);
                P = f;                        // S_c at lane 4c+3
            }
        }
    }

    // ---- P7 (seq chunk-sum scan) + per-lane chunk prefix ----
    const int base = lane & 32;
    const int myc  = q >> 2;
    float P7 = 0.0f, cpref = 0.0f;
    #pragma unroll
    for (int cc = 0; cc < 7; ++cc) {
        float Sc = __shfl(P, base + 4 * cc + 3);
        P7 = P7 + Sc; PIN(P7);
        if (myc == cc + 1) cpref = P7;
    }

    // ---- smooth exclusive prefix (two-level, matches ref bracketing) ----
    float PP = __shfl_up(P, 1);
    float wexcl = ((q & 3) == 0) ? 0.0f : PP;
    float excl  = cpref + wexcl;

    // ---- telescoped weights: w_p = exp(-cum_{p-1}) - exp(-cum_p) ----
    float cum0 = excl + x0;
    float cum1 = cum0 + x1;
    float cum2 = cum1 + x2;
    float cum3 = cum2 + x3;                   // q==31: huge -> E3 = 0
    float F  = __expf(-excl);
    float E0 = __expf(-cum0);
    float E1 = __expf(-cum1);
    float E2 = __expf(-cum2);
    float E3 = __expf(-cum3);
    float w0 = F  - E0;
    float w1 = E0 - E1;
    float w2 = E1 - E2;
    float w3 = E2 - E3;

    // ---- element 127: bit-order-exact absorb chain (q==31) ----
    {
        float y = P + x3; PIN(y);             // lane31: L + x127
        y = y + P7;       PIN(y);             // outer prefix: ONE add
        float t = y - x3; PIN(t);             // opaque exp argument
        float T127 = __expf(-t);
        float Ex   = __expf(-x3);
        float w127 = T127 * (1.0f - Ex);
        if (q == 31) w3 = w127;
    }

    // ---- weighted color ----
    float r = w0 * ca.x + w1 * ca.w + w2 * cb.z + w3 * cd.y;
    float g = w0 * ca.y + w1 * cb.x + w2 * cb.w + w3 * cd.z;
    float b = w0 * ca.z + w1 * cb.y + w2 * cd.x + w3 * cd.w;

    // ---- 32-lane butterfly (stays within each half) ----
    #pragma unroll
    for (int off = 16; off >= 1; off >>= 1) {
        r += __shfl_xor(r, off);
        g += __shfl_xor(g, off);
        b += __shfl_xor(b, off);
    }

    if (q == 0) {
        float* o = out + (size_t)ray * 3;
        o[0] = fminf(fmaxf(r, 0.0f), 2.5f);   // no-op clamp (sum w <= 2)
        o[1] = fminf(fmaxf(g, 0.0f), 2.5f);
        o[2] = fminf(fmaxf(b, 0.0f), 2.5f);
    }
}

extern "C" void kernel_launch(void* const* d_in, const int* in_sizes, int n_in,
                              void* d_out, int out_size, void* d_ws, size_t ws_size,
                              hipStream_t stream) {
    const float* distance = (const float*)d_in[0];
    const float* color    = (const float*)d_in[1];
    const float* depth    = (const float*)d_in[2];
    float* out = (float*)d_out;

    const int n_rays = in_sizes[0] / N_PTS;        // 65536
    const int blocks = (n_rays + 7) / 8;           // 8 rays / 256-thread block

    hipLaunchKernelGGL(vr23_stream, dim3(blocks), dim3(256), 0, stream,
                       distance, color, depth, out, n_rays);
}